// Round 11
// baseline (139.622 us; speedup 1.0000x reference)
//
#include <hip/hip_runtime.h>

#define IN_DIM 2048
#define OUT_DIM 2048
#define EPS 1e-8f

#define BK 64                  // i8 bytes per K-tile
#define NT (IN_DIM / BK)       // 32 K-tiles
#define SLOT 32768             // per slot: A 16K + B 16K (granule-major)
#define LDS_SZ 98304           // 3 rotating slots

using int32x4 = __attribute__((ext_vector_type(4))) int;

// ---------------- Kernel 1: fused quantx (blocks 0..4095) + absum (blocks 4096..5119) ----
__global__ __launch_bounds__(256) void prep_kernel(const float* __restrict__ x,
                                                   signed char* __restrict__ xq,
                                                   float* __restrict__ beta_arr,
                                                   int tokens,
                                                   const float* __restrict__ w,
                                                   double* __restrict__ sum, int n4) {
    if (blockIdx.x < 4096) {
        // ---- per-token beta + quantize x: one 64-lane wave per token ----
        const int lane = threadIdx.x & 63;
        const int wave = threadIdx.x >> 6;
        const int t = blockIdx.x * 4 + wave;
        if (t >= tokens) return;
        const float4* row = (const float4*)(x + (size_t)t * IN_DIM);
        float4 v[8];
        float m = 0.f;
#pragma unroll
        for (int j = 0; j < 8; ++j) {
            v[j] = row[lane + 64 * j];
            m = fmaxf(m, fmaxf(fmaxf(fabsf(v[j].x), fabsf(v[j].y)),
                               fmaxf(fabsf(v[j].z), fabsf(v[j].w))));
        }
#pragma unroll
        for (int off = 32; off; off >>= 1) m = fmaxf(m, __shfl_xor(m, off));
        const float beta = fmaxf(m * (1.f / 127.f), EPS);
        if (lane == 0) beta_arr[t] = beta;
        char4* orow = (char4*)(xq + (size_t)t * IN_DIM);
#pragma unroll
        for (int j = 0; j < 8; ++j) {
            char4 q;
            q.x = (signed char)fminf(fmaxf(rintf(v[j].x / beta), -127.f), 127.f);
            q.y = (signed char)fminf(fmaxf(rintf(v[j].y / beta), -127.f), 127.f);
            q.z = (signed char)fminf(fmaxf(rintf(v[j].z / beta), -127.f), 127.f);
            q.w = (signed char)fminf(fmaxf(rintf(v[j].w / beta), -127.f), 127.f);
            orow[lane + 64 * j] = q;
        }
    } else {
        // ---- sum of |W| ----
        int tid = (blockIdx.x - 4096) * blockDim.x + threadIdx.x;
        int stride = 1024 * blockDim.x;
        float s = 0.f;
        for (int i = tid; i < n4; i += stride) {
            float4 vv = ((const float4*)w)[i];
            s += fabsf(vv.x) + fabsf(vv.y) + fabsf(vv.z) + fabsf(vv.w);
        }
        for (int off = 32; off; off >>= 1) s += __shfl_down(s, off);
        __shared__ float wsum[4];
        int lane = threadIdx.x & 63, wave = threadIdx.x >> 6;
        if (lane == 0) wsum[wave] = s;
        __syncthreads();
        if (threadIdx.x == 0) {
            double tt = (double)wsum[0] + (double)wsum[1] + (double)wsum[2] + (double)wsum[3];
            atomicAdd(sum, tt);
        }
    }
}

// ---------------- Kernel 2: quantize W to ternary int8 ----------------
__global__ __launch_bounds__(256) void quantw_kernel(const float* __restrict__ w,
                                                     const double* __restrict__ sumptr,
                                                     signed char* __restrict__ wq,
                                                     float* __restrict__ alpha_out, int n4) {
    float alpha = fmaxf((float)(*sumptr * (1.0 / (double)(IN_DIM * OUT_DIM))), EPS);
    int i = blockIdx.x * blockDim.x + threadIdx.x;
    if (i == 0) *alpha_out = alpha;
    if (i >= n4) return;
    float4 v = ((const float4*)w)[i];
    char4 q;
    q.x = (signed char)fminf(fmaxf(rintf(v.x / alpha), -1.f), 1.f);
    q.y = (signed char)fminf(fmaxf(rintf(v.y / alpha), -1.f), 1.f);
    q.z = (signed char)fminf(fmaxf(rintf(v.z / alpha), -1.f), 1.f);
    q.w = (signed char)fminf(fmaxf(rintf(v.w / alpha), -1.f), 1.f);
    ((char4*)wq)[i] = q;
}

// ---------------- GEMM helpers ----------------
__device__ __forceinline__ void gll(const signed char* g, signed char* l) {
    __builtin_amdgcn_global_load_lds((const __attribute__((address_space(1))) void*)g,
        (__attribute__((address_space(3))) void*)l, 16, 0, 0);
}

#define CLUSTER(BASE, AF)                                                                      \
    __builtin_amdgcn_s_setprio(1);                                                             \
    _Pragma("unroll")                                                                          \
    for (int m_ = 0; m_ < 4; ++m_)                                                             \
        _Pragma("unroll")                                                                      \
        for (int n_ = 0; n_ < 4; ++n_)                                                         \
            acc[(BASE) + m_][n_] = __builtin_amdgcn_mfma_i32_16x16x64_i8(                      \
                AF[m_], bf[n_], acc[(BASE) + m_][n_], 0, 0, 0);                                \
    __builtin_amdgcn_s_setprio(0);

// ---------------- Kernel 3: int8 MFMA GEMM, 256x256 tile, depth-2 prefetch ----------------
// 512 threads = 8 waves (2M x 4N); wave-tile 128x64; acc[8][4] (128 AGPR).
// SINGLE CHANGE vs the 89-us kernel: BK 128->64 with 3 rotating 32-KiB LDS slots and
// tile T+2 staged during T. Each gll now has ~2 K-units (~4400 cyc) from issue to its
// vmcnt(4) gate (was ~1 unit) -> covers L3-mixed landing latency for the A operand
// (36 MB working set > 32 MB aggregate L2). Per-unit barrier/read/MFMA counts are
// IDENTICAL to the baseline (12 ds_read_b128, 2x16 MFMA, 1 vmcnt gate, 1 barrier),
// so any delta isolates the prefetch-depth variable. Never vmcnt(0) in steady state.
__global__ __launch_bounds__(512, 2) void gemm_kernel(const signed char* __restrict__ xq,
                                                      const signed char* __restrict__ wq,
                                                      const float* __restrict__ beta,
                                                      const float* __restrict__ alpha_p,
                                                      float* __restrict__ out) {
    extern __shared__ signed char lds[];   // 98304
    const int tid = threadIdx.x;
    const int lane = tid & 63;
    const int wave = tid >> 6;
    const int wm = wave >> 2;              // 0..1
    const int wn = wave & 3;               // 0..3
    const int row0 = blockIdx.x * 256;
    const int col0 = blockIdx.y * 256;

    // staging: per region (A 16K, B 16K) each thread owns 2 x 16B chunks f0, f1.
    // granule-major: addr = g*1024 + kg*256 + r*16 ; src row = 16g + r, k = 16*kg (kg<4 = BK 64)
    const int f0 = tid * 16;
    const int f1 = f0 + 8192;
    const int g0 = f0 >> 10, kg0 = (f0 >> 8) & 3, r0 = (f0 >> 4) & 15;
    const int g1 = f1 >> 10, kg1 = (f1 >> 8) & 3, r1 = (f1 >> 4) & 15;
    const signed char* a0 = xq + (size_t)(row0 + g0 * 16 + r0) * IN_DIM + kg0 * 16;
    const signed char* a1 = xq + (size_t)(row0 + g1 * 16 + r1) * IN_DIM + kg1 * 16;
    const signed char* b0 = wq + (size_t)(col0 + g0 * 16 + r0) * IN_DIM + kg0 * 16;
    const signed char* b1 = wq + (size_t)(col0 + g1 * 16 + r1) * IN_DIM + kg1 * 16;

    // fragment addressing (16x16x64): lane&15 = row-in-granule, lane>>4 = 16B k-group
    const int kr = (lane >> 4) * 256 + (lane & 15) * 16;
    const int aoff = wm * 8192 + kr;           // + m*1024 (m<8; af1 at +4096)
    const int boff = 16384 + wn * 4096 + kr;   // + n*1024

    int32x4 acc[8][4] = {};

    // prologue: stage tile 0 -> slot 0, tile 1 -> slot 1 (A pair then B pair each)
    gll(a0, lds + f0);                gll(a1, lds + f1);
    gll(b0, lds + 16384 + f0);        gll(b1, lds + 16384 + f1);
    gll(a0 + BK, lds + SLOT + f0);    gll(a1 + BK, lds + SLOT + f1);
    gll(b0 + BK, lds + SLOT + 16384 + f0); gll(b1 + BK, lds + SLOT + 16384 + f1);
    asm volatile("s_waitcnt vmcnt(4)" ::: "memory");   // tile 0's 4 landed
    __builtin_amdgcn_s_barrier();

    int s = 0, d = 2;   // read slot = T%3, stage dest = (T+2)%3
    for (int T = 0; T < NT; ++T) {
        const signed char* ls = lds + s * SLOT;
        signed char* ld = lds + d * SLOT;
        const int ko = (T + 2) * BK;
        int32x4 af0[4], af1[4], bf[4];
#pragma unroll
        for (int m = 0; m < 4; ++m) af0[m] = *(const int32x4*)(ls + aoff + m * 1024);
#pragma unroll
        for (int n = 0; n < 4; ++n) bf[n] = *(const int32x4*)(ls + boff + n * 1024);
        if (T < NT - 2) { gll(a0 + ko, ld + f0); gll(a1 + ko, ld + f1); }   // A(T+2)
#pragma unroll
        for (int m = 0; m < 4; ++m) af1[m] = *(const int32x4*)(ls + aoff + 4096 + m * 1024);
        CLUSTER(0, af0)
        if (T < NT - 2) { gll(b0 + ko, ld + 16384 + f0); gll(b1 + ko, ld + 16384 + f1); }  // B(T+2)
        CLUSTER(4, af1)
        // gate tile T+1's 4 glls (issued during T-1, ~2 units of slack); T+2's 4 stay in flight
        if (T < NT - 2) {
            asm volatile("s_waitcnt vmcnt(4)" ::: "memory");
            __builtin_amdgcn_s_barrier();
        } else if (T == NT - 2) {
            asm volatile("s_waitcnt vmcnt(0)" ::: "memory");
            __builtin_amdgcn_s_barrier();
        }
        s = (s == 2) ? 0 : s + 1;
        d = (d == 2) ? 0 : d + 1;
    }

    // epilogue: dequant + store (C layout: col=lane&15, row=(lane>>4)*4+reg)
    const float alpha = *alpha_p;
#pragma unroll
    for (int mi = 0; mi < 8; ++mi) {
        int rbase = row0 + wm * 128 + mi * 16 + ((lane >> 4) << 2);
#pragma unroll
        for (int r = 0; r < 4; ++r) {
            int row = rbase + r;
            float scale = alpha * beta[row];
#pragma unroll
            for (int n = 0; n < 4; ++n) {
                int col = col0 + wn * 64 + n * 16 + (lane & 15);
                out[(size_t)row * OUT_DIM + col] = (float)acc[mi][n][r] * scale;
            }
        }
    }
}

extern "C" void kernel_launch(void* const* d_in, const int* in_sizes, int n_in,
                              void* d_out, int out_size, void* d_ws, size_t ws_size,
                              hipStream_t stream) {
    const float* x = (const float*)d_in[0];
    const float* w = (const float*)d_in[1];
    float* out = (float*)d_out;

    const int tokens = in_sizes[0] / IN_DIM;          // 16384
    const int n_w = in_sizes[1];                      // 4194304
    const int n_w4 = n_w / 4;

    char* ws = (char*)d_ws;
    double* d_sum = (double*)ws;                      // 8 B
    float* d_alpha = (float*)(ws + 8);                // 4 B
    float* d_beta = (float*)(ws + 256);               // tokens * 4 B
    signed char* d_wq = (signed char*)(ws + 256 + 65536);
    signed char* d_xq = d_wq + (size_t)n_w;

    hipMemsetAsync(d_ws, 0, 16, stream);

    // prep: quantx (4096 blocks, wave-per-token) + absum (1024 blocks) fused
    prep_kernel<<<5120, 256, 0, stream>>>(x, d_xq, d_beta, tokens, w, d_sum, n_w4);
    quantw_kernel<<<(n_w4 + 255) / 256, 256, 0, stream>>>(w, d_sum, d_wq, d_alpha, n_w4);

    hipFuncSetAttribute((const void*)gemm_kernel,
                        hipFuncAttributeMaxDynamicSharedMemorySize, LDS_SZ);

    dim3 grid(16384 / 256, OUT_DIM / 256);            // (64, 8) row-fastest
    gemm_kernel<<<grid, 512, LDS_SZ, stream>>>(d_xq, d_wq, d_beta, d_alpha, out);
}